// Round 8
// baseline (12579.631 us; speedup 1.0000x reference)
//
#include <hip/hip_runtime.h>
#include <hip/hip_fp16.h>
#include <math.h>

typedef _Float16 h16;
typedef __attribute__((ext_vector_type(4))) _Float16 h16x4;
typedef __attribute__((ext_vector_type(8))) _Float16 h16x8;
typedef __attribute__((ext_vector_type(4))) float f32x4;
typedef unsigned long long u64;

#define T_SEQ 512
#define NB    64
#define NI    512
#define NH    1024
#define N3H   3072

// ---- coherence tiers ----
// sc1 tier (LLC, cross-XCD): agent-scope relaxed atomics.
__device__ __forceinline__ u64 cload64(const u64* p) {
  return __hip_atomic_load(p, __ATOMIC_RELAXED, __HIP_MEMORY_SCOPE_AGENT);
}
__device__ __forceinline__ void cstore64(u64* p, u64 v) {
  __hip_atomic_store(p, v, __ATOMIC_RELAXED, __HIP_MEMORY_SCOPE_AGENT);
}
// sc0 tier (same-XCD L2): L1-bypass load; paired with explicit vmcnt + pin.
__device__ __forceinline__ u64 l2load64(const u64* p) {
  u64 v;
  asm volatile("global_load_dwordx2 %0, %1, off sc0" : "=v"(v) : "v"(p));
  return v;
}
__device__ __forceinline__ void vmwait0() {
  asm volatile("s_waitcnt vmcnt(0)" ::: "memory");
}
__device__ __forceinline__ void pin64(u64& v) {   // order value after prior volatile asm
  asm volatile("" : "+v"(v));
}

union H4 { u64 q; h16x4 v; };

// h word: lo u32 = q0[0:14)|q1[14:28)|tag[28:32), hi u32 = q2|q3<<14.
// q = rint(h*8192) 14-bit 2c; tag = (producing_step>>1)&15.

// ============================================================
// Kernel 0: init h^(0) plane (parity 0) packed-frag order, tag 0.
// ============================================================
__global__ void gru_init_h(const float* __restrict__ hid0,
                           u64* __restrict__ hfrag) {
  int w = blockIdx.x * blockDim.x + threadIdx.x;   // 0..16383
  if (w >= 16384) return;
  int l  = w & 63;
  int cg = (w & 4095) >> 6;
  int cb = cg * 16 + ((l >> 5) << 3) + ((l & 1) << 2);
  unsigned q[4];
  #pragma unroll
  for (int j = 0; j < 4; ++j) {
    float v = fminf(fmaxf(hid0[cb + j] * 8192.0f, -8192.0f), 8191.0f);
    q[j] = (unsigned)((int)__builtin_rintf(v)) & 0x3FFFu;
  }
  unsigned lo = q[0] | (q[1] << 14);               // tag = 0
  unsigned hi = q[2] | (q[3] << 14);
  hfrag[w] = (u64)lo | ((u64)hi << 32);
}

// ============================================================
// Kernel 1: x = inp @ W_in + b  (f16 out, CONSUMER-TRANSPOSED layout)
// ============================================================
#define P1_BM 128
#define P1_BK 32

__device__ __forceinline__ int p1swz(int r, int k) {
  return r * P1_BK + ((((k >> 3) ^ (r & 3)) << 3) | (k & 7));
}

__global__ __launch_bounds__(256, 2) void gru_xgemm(
    const float* __restrict__ inp, const float* __restrict__ Win,
    const float* __restrict__ bstk, h16* __restrict__ x) {
  __shared__ h16 sAh[2][P1_BM * P1_BK];
  __shared__ h16 sAl[2][P1_BM * P1_BK];
  __shared__ h16 sBh[2][P1_BM * P1_BK];
  __shared__ h16 sBl[2][P1_BM * P1_BK];

  const int tid = threadIdx.x;
  const int l = tid & 63;
  const int w = tid >> 6;
  const int wm = (w >> 1) * 64, wn = (w & 1) * 64;
  const int mi = blockIdx.x, ni = blockIdx.y;

  const int sr  = tid >> 1;
  const int skh = (tid & 1) * 16;

  const float* aSrcBase = inp + (size_t)(sr & 63) * (T_SEQ * NI)
                              + (size_t)(mi * 2 + (sr >> 6)) * NI + skh;
  const float* bSrcBase = Win + (size_t)skh * N3H + ni * 128 + sr;

  f32x4 acc[4][4] = {};
  float aReg[16];
  float bReg[16];

  auto stage_load = [&](int ks) {
    const float* ap = aSrcBase + ks * P1_BK;
    #pragma unroll
    for (int jg = 0; jg < 4; ++jg) {
      f32x4 v = *(const f32x4*)(ap + jg * 4);
      aReg[jg*4+0] = v[0]; aReg[jg*4+1] = v[1];
      aReg[jg*4+2] = v[2]; aReg[jg*4+3] = v[3];
    }
    const float* bp = bSrcBase + (size_t)ks * P1_BK * N3H;
    #pragma unroll
    for (int j = 0; j < 16; ++j) bReg[j] = bp[(size_t)j * N3H];
  };

  auto stage_write = [&](int buf) {
    #pragma unroll
    for (int jg = 0; jg < 4; ++jg) {
      int idx = p1swz(sr, skh + jg * 4);
      h16x4 hi, lo;
      #pragma unroll
      for (int j = 0; j < 4; ++j) {
        float v = aReg[jg*4+j];
        h16 h = (h16)v; hi[j] = h; lo[j] = (h16)(v - (float)h);
      }
      *(h16x4*)&sAh[buf][idx] = hi;
      *(h16x4*)&sAl[buf][idx] = lo;
      #pragma unroll
      for (int j = 0; j < 4; ++j) {
        float v = bReg[jg*4+j];
        h16 h = (h16)v; hi[j] = h; lo[j] = (h16)(v - (float)h);
      }
      *(h16x4*)&sBh[buf][idx] = hi;
      *(h16x4*)&sBl[buf][idx] = lo;
    }
  };

  auto compute = [&](int buf) {
    const int k0 = (l >> 4) * 8;
    h16x8 bh[4], bl[4];
    #pragma unroll
    for (int nt = 0; nt < 4; ++nt) {
      int idx = p1swz(wn + nt * 16 + (l & 15), k0);
      bh[nt] = *(const h16x8*)&sBh[buf][idx];
      bl[nt] = *(const h16x8*)&sBl[buf][idx];
    }
    #pragma unroll
    for (int mt = 0; mt < 4; ++mt) {
      int idx = p1swz(wm + mt * 16 + (l & 15), k0);
      h16x8 ah = *(const h16x8*)&sAh[buf][idx];
      h16x8 al = *(const h16x8*)&sAl[buf][idx];
      #pragma unroll
      for (int nt = 0; nt < 4; ++nt) {
        acc[mt][nt] = __builtin_amdgcn_mfma_f32_16x16x32_f16(ah, bh[nt], acc[mt][nt], 0, 0, 0);
        acc[mt][nt] = __builtin_amdgcn_mfma_f32_16x16x32_f16(ah, bl[nt], acc[mt][nt], 0, 0, 0);
        acc[mt][nt] = __builtin_amdgcn_mfma_f32_16x16x32_f16(al, bh[nt], acc[mt][nt], 0, 0, 0);
      }
    }
  };

  stage_load(0);
  stage_write(0);
  __syncthreads();
  for (int ks = 0; ks < 16; ++ks) {
    int buf = ks & 1;
    if (ks < 15) stage_load(ks + 1);
    compute(buf);
    if (ks < 15) stage_write(buf ^ 1);
    __syncthreads();
  }

  const int t = mi * 2 + (wm >> 6);
  const int rrb = (l >> 4) * 4;
  #pragma unroll
  for (int nt = 0; nt < 4; ++nt) {
    int colhi = ni * 8 + (wn >> 4) + nt;
    int gg  = colhi >> 6;
    int cgx = colhi & 63;
    float bias = bstk[(colhi << 4) + (l & 15)];
    #pragma unroll
    for (int mt = 0; mt < 4; ++mt) {
      h16x4 v;
      #pragma unroll
      for (int i = 0; i < 4; ++i) v[i] = (h16)(acc[mt][nt][i] + bias);
      size_t idx = ((((size_t)t * 3 + gg) * 64 + cgx) * 4 + mt) * 256
                 + (size_t)(l & 15) * 16 + rrb;
      *(h16x4*)&x[idx] = v;
    }
  }
}

// ============================================================
// Kernel 2: persistent GRU recurrence, self-validating h words,
// TWO-TIER broadcast: per-(XCD,ring) relay copies the LLC plane into
// an XCD-local L2 buffer; consumers poll L2 (sc0) with per-word
// fallback to the LLC tier (correct under any WG->XCD mapping).
// ============================================================
__global__ __launch_bounds__(192, 1) void gru_steps(
    const float* __restrict__ Whid,   // [1024][3072] f32
    const h16* __restrict__ x,        // transposed layout, f16
    u64* __restrict__ hfrag,          // [2 par][4 bg][4096] u64 (LLC tier)
    u64* __restrict__ xcdbuf,         // [8 xcd][4 bg][2 par][4096] u64 (L2 tier)
    unsigned* __restrict__ claim,     // [8][4] relay election
    const float* __restrict__ hid0,   // [1024]
    float* __restrict__ out) {        // [64][1024] f32
  __shared__ h16 U[3 * 32 * 64 * 8];  // 96 KiB fragment-ordered W_hid slice
  __shared__ h16 hstage[16384];       // 32 KiB unpacked h plane (frag order)
  __shared__ float rbuf[2][16 * 17];
  __shared__ float ubuf[2][16 * 17];
  __shared__ unsigned short tq[16 * 20];
  __shared__ unsigned sXcd, sRelay;

  const int tid = threadIdx.x;
  const int l = tid & 63;
  const int g = tid >> 6;
  const int cg = blockIdx.x & 63;
  const int bg = blockIdx.x >> 6;

  // ---- one-time: W_hid slice -> fragment-ordered LDS ----
  {
    const float* base = Whid + (size_t)g * NH + (size_t)cg * 16 + (l & 15);
    for (int kt = 0; kt < 32; ++kt) {
      const float* src = base + (size_t)(kt * 32 + (l >> 4) * 8) * N3H;
      h16x8 v;
      #pragma unroll
      for (int j = 0; j < 8; ++j) v[j] = (h16)src[(size_t)j * N3H];
      *(h16x8*)&U[(size_t)((g * 32 + kt) * 64 + l) * 8] = v;
    }
  }

  // ---- relay election: true XCD id + CAS claim per (xcd, ring) ----
  if (tid == 0) {
    unsigned xcc;
    asm volatile("s_getreg_b32 %0, hwreg(20, 0, 32)" : "=s"(xcc));  // XCC_ID
    xcc &= 7u;
    unsigned expd = 0xFFFFFFFFu;
    bool won = __hip_atomic_compare_exchange_strong(
        &claim[xcc * 4 + bg], &expd, 1u,
        __ATOMIC_RELAXED, __ATOMIC_RELAXED, __HIP_MEMORY_SCOPE_AGENT);
    sXcd = xcc;
    sRelay = won ? 1u : 0u;
  }

  const int rr0 = (l >> 4) * 4, cc = l & 15;

  // ---- wave2: persistent f32 h_prev registers (owner-only tile) ----
  float hq[4];
  if (g == 2) {
    float h0 = hid0[cg * 16 + cc];
    #pragma unroll
    for (int i = 0; i < 4; ++i) hq[i] = h0;
  }
  __syncthreads();
  const unsigned xcd = sXcd;
  const bool isRelay = (sRelay != 0);

  // x pointer for this wave (one 8B load per step)
  const char* xb = (const char*)(x
      + ((((size_t)g * 64 + cg) * 4 + bg) * 256)
      + (size_t)cc * 16 + rr0);
  u64 xq = *(const u64*)xb;   // step-1 tile, prefetched

  const h16* Ug = &U[(size_t)g * 32 * 64 * 8];
  const float S = 1.0f / 8192.0f;

  for (int s = 1; s <= T_SEQ; ++s) {
    const int par = (s - 1) & 1;
    const u64* src = hfrag + ((size_t)par * 4 + bg) * 4096;           // LLC tier
    u64* xb2 = xcdbuf + (((size_t)xcd * 4 + bg) * 2 + par) * 4096;    // L2 tier
    const unsigned expt = (((unsigned)(s - 1)) >> 1) & 15u;

    // prefetch next step's x tile (plain cached load, independent)
    u64 xq_next = xq;
    if (s < T_SEQ) xq_next = *(const u64*)(xb + (size_t)s * 393216);

    u64 w[22];
    if (isRelay) {
      // ---- relay: validated sc1 read from LLC, republish raw to L2 ----
      #pragma unroll
      for (int k = 0; k < 22; ++k) {
        int wd = tid + 192 * k;
        w[k] = (wd < 4096) ? cload64(src + wd) : ((u64)expt << 28);
      }
      for (int tries = 0; tries < 20000; ++tries) {
        unsigned bad = 0;
        #pragma unroll
        for (int k = 0; k < 22; ++k)
          bad |= ((((unsigned)(w[k] >> 28)) & 15u) != expt) ? (1u << k) : 0u;
        if (bad == 0) break;
        #pragma unroll
        for (int k = 0; k < 22; ++k) {
          int wd = tid + 192 * k;
          if ((bad & (1u << k)) && wd < 4096) w[k] = cload64(src + wd);
        }
      }
      #pragma unroll
      for (int k = 0; k < 22; ++k) {
        int wd = tid + 192 * k;
        if (wd < 4096) xb2[wd] = w[k];    // plain store -> own-XCD L2
      }
    } else {
      // ---- consumer: poll L2 tier, per-word fallback to LLC tier ----
      #pragma unroll
      for (int k = 0; k < 22; ++k) {
        int wd = tid + 192 * k;
        w[k] = (wd < 4096) ? l2load64(xb2 + wd) : ((u64)expt << 28);
      }
      vmwait0();
      #pragma unroll
      for (int k = 0; k < 22; ++k) pin64(w[k]);
      for (int tries = 0; tries < 20000; ++tries) {
        unsigned bad = 0;
        #pragma unroll
        for (int k = 0; k < 22; ++k)
          bad |= ((((unsigned)(w[k] >> 28)) & 15u) != expt) ? (1u << k) : 0u;
        if (bad == 0) break;
        if (tries < 24) {
          #pragma unroll
          for (int k = 0; k < 22; ++k) {
            int wd = tid + 192 * k;
            if ((bad & (1u << k)) && wd < 4096) w[k] = l2load64(xb2 + wd);
          }
          vmwait0();
          #pragma unroll
          for (int k = 0; k < 22; ++k) pin64(w[k]);
        } else {
          #pragma unroll
          for (int k = 0; k < 22; ++k) {
            int wd = tid + 192 * k;
            if ((bad & (1u << k)) && wd < 4096) w[k] = cload64(src + wd);
          }
        }
      }
    }

    // ---- unpack q14 -> f16 frag into LDS ----
    #pragma unroll
    for (int k = 0; k < 22; ++k) {
      int wd = tid + 192 * k;
      if (wd < 4096) {
        unsigned lo = (unsigned)w[k], hi = (unsigned)(w[k] >> 32);
        h16x4 o;
        o[0] = (h16)((float)(((int)(lo << 18)) >> 18) * S);
        o[1] = (h16)((float)(((int)(lo << 4)) >> 18) * S);
        o[2] = (h16)((float)(((int)(hi << 18)) >> 18) * S);
        o[3] = (h16)((float)(((int)(hi << 4)) >> 18) * S);
        *(h16x4*)&hstage[wd * 4] = o;
      }
    }
    __syncthreads();   // b1: h staged

    // ---- hid = h_f16 @ U_gate : 32 MFMA, contiguous b128 reads ----
    f32x4 a0 = {}, a1 = {};
    #pragma unroll
    for (int kt = 0; kt < 32; ++kt) {
      h16x8 a = *(const h16x8*)&hstage[(kt * 64 + l) * 8];
      h16x8 b = *(const h16x8*)&Ug[(kt * 64 + l) * 8];
      if (kt & 1) a1 = __builtin_amdgcn_mfma_f32_16x16x32_f16(a, b, a1, 0, 0, 0);
      else        a0 = __builtin_amdgcn_mfma_f32_16x16x32_f16(a, b, a0, 0, 0, 0);
    }
    f32x4 hid;
    #pragma unroll
    for (int i = 0; i < 4; ++i) hid[i] = a0[i] + a1[i];

    H4 xc; xc.q = xq;
    const int p = s & 1;

    if (g == 0) {
      #pragma unroll
      for (int i = 0; i < 4; ++i) {
        float pr = (float)xc.v[i] + hid[i];
        rbuf[p][(rr0 + i) * 17 + cc] = 1.0f / (1.0f + __expf(-pr));
      }
    } else if (g == 1) {
      #pragma unroll
      for (int i = 0; i < 4; ++i) {
        float pu = (float)xc.v[i] + hid[i];
        ubuf[p][(rr0 + i) * 17 + cc] = 1.0f / (1.0f + __expf(-pu));
      }
    }
    __syncthreads();   // b2: r,u visible to wave 2

    if (g == 2) {
      const unsigned tag = (((unsigned)s) >> 1) & 15u;
      #pragma unroll
      for (int i = 0; i < 4; ++i) {
        int rr = rr0 + i;
        float r = rbuf[p][rr * 17 + cc];
        float u = ubuf[p][rr * 17 + cc];
        float z = (float)xc.v[i] + r * hid[i];
        float e = __expf(2.0f * z);
        float c = 1.0f - 2.0f / (e + 1.0f);      // tanh(z)
        float hn = (1.0f - u) * hq[i] + u * c;
        hq[i] = hn;
        int qv = (int)__builtin_rintf(fminf(hn * 8192.0f, 8191.0f));
        tq[rr * 20 + cc] = (unsigned short)(qv & 0x3FFF);
        if (s == T_SEQ) out[(size_t)(bg * 16 + rr) * NH + cg * 16 + cc] = hn;
      }
      u64 t = *(const u64*)&tq[((l >> 1) & 15) * 20 + (l >> 5) * 8 + (l & 1) * 4];
      unsigned lo = ((unsigned)t & 0x3FFFu)
                  | ((((unsigned)(t >> 16)) & 0x3FFFu) << 14) | (tag << 28);
      unsigned hi = (((unsigned)(t >> 32)) & 0x3FFFu)
                  | ((((unsigned)(t >> 48)) & 0x3FFFu) << 14);
      u64* dst = hfrag + (((size_t)(s & 1) * 4 + bg) * 4096) + cg * 64 + l;
      cstore64(dst, (u64)lo | ((u64)hi << 32));   // self-validating, sc1 tier
    }
    xq = xq_next;
  }
}

// ============================================================
extern "C" void kernel_launch(void* const* d_in, const int* in_sizes, int n_in,
                              void* d_out, int out_size, void* d_ws, size_t ws_size,
                              hipStream_t stream) {
  const float* inp  = (const float*)d_in[0];
  const float* Win  = (const float*)d_in[1];
  const float* Whid = (const float*)d_in[2];
  const float* bstk = (const float*)d_in[3];
  const float* hid0 = (const float*)d_in[4];
  float* out = (float*)d_out;

  char* ws = (char*)d_ws;
  const size_t xBytes = (size_t)T_SEQ * NB * N3H * sizeof(h16);   // 201,326,592
  const size_t hBytes = (size_t)2 * 4 * 4096 * sizeof(u64);       //     262,144
  const size_t bBytes = (size_t)8 * 4 * 2 * 4096 * sizeof(u64);   //   2,097,152
  const size_t cBytes = 8 * 4 * sizeof(unsigned);                 //         128
  if (ws_size < xBytes + hBytes + bBytes + cBytes) return;

  h16* x = (h16*)ws;
  u64* hfrag = (u64*)(ws + xBytes);
  u64* xcdbuf = (u64*)(ws + xBytes + hBytes);
  unsigned* claim = (unsigned*)(ws + xBytes + hBytes + bBytes);

  hipMemsetAsync(claim, 0xFF, cBytes, stream);   // re-elect relays each launch

  gru_init_h<<<dim3(16384 / 256), dim3(256), 0, stream>>>(hid0, hfrag);

  dim3 g1(32768 / P1_BM, N3H / 128);
  gru_xgemm<<<g1, dim3(256), 0, stream>>>(inp, Win, bstk, x);

  gru_steps<<<dim3(256), dim3(192), 0, stream>>>(Whid, x, hfrag, xcdbuf,
                                                 claim, hid0, out);
}

// Round 9
// 2822.558 us; speedup vs baseline: 4.4568x; 4.4568x over previous
//
#include <hip/hip_runtime.h>
#include <hip/hip_fp16.h>
#include <math.h>

typedef _Float16 h16;
typedef __attribute__((ext_vector_type(4))) _Float16 h16x4;
typedef __attribute__((ext_vector_type(8))) _Float16 h16x8;
typedef __attribute__((ext_vector_type(4))) float f32x4;
typedef unsigned long long u64;

#define T_SEQ 512
#define NB    64
#define NI    512
#define NH    1024
#define N3H   3072

// Agent-scope (LLC-coherent) access helpers. Relaxed per-access coherence
// only — no cache-wide fences (round-2 lesson), no L2 relay tier (round-8
// lesson: sc0 re-loads L1-serve stale data on gfx950).
__device__ __forceinline__ u64 cload64(const u64* p) {
  return __hip_atomic_load(p, __ATOMIC_RELAXED, __HIP_MEMORY_SCOPE_AGENT);
}
__device__ __forceinline__ void cstore64(u64* p, u64 v) {
  __hip_atomic_store(p, v, __ATOMIC_RELAXED, __HIP_MEMORY_SCOPE_AGENT);
}

union H4 { u64 q; h16x4 v; };

// h word (u64 = 4 h-values of one row, 4 consecutive cols):
//   lo u32: q0[0:14) | q1[14:28) | tag[28:32)   q = rint(h*8192), 14-bit 2c
//   hi u32: q2[0:14) | q3[14:28) | 0
// tag = (producing_step >> 1) & 15  (epoch of this parity plane).

// ============================================================
// Kernel 0: init h^(0) plane (parity 0) packed-frag order, tag 0.
// word w: bg=w>>12, cg=(w&4095)>>6, l=w&63; row=(l>>1)&15,
// cols cg*16+(l>>5)*8+(l&1)*4.
// ============================================================
__global__ void gru_init_h(const float* __restrict__ hid0,
                           u64* __restrict__ hfrag) {
  int w = blockIdx.x * blockDim.x + threadIdx.x;   // 0..16383
  if (w >= 16384) return;
  int l  = w & 63;
  int cg = (w & 4095) >> 6;
  int cb = cg * 16 + ((l >> 5) << 3) + ((l & 1) << 2);
  unsigned q[4];
  #pragma unroll
  for (int j = 0; j < 4; ++j) {
    float v = fminf(fmaxf(hid0[cb + j] * 8192.0f, -8192.0f), 8191.0f);
    q[j] = (unsigned)((int)__builtin_rintf(v)) & 0x3FFFu;
  }
  unsigned lo = q[0] | (q[1] << 14);               // tag = 0
  unsigned hi = q[2] | (q[3] << 14);
  hfrag[w] = (u64)lo | ((u64)hi << 32);
}

// ============================================================
// Kernel 1: x = inp @ W_in + b  (f16 out, CONSUMER-TRANSPOSED layout)
// x layout: [t][gate][cg][bg][cc*16 + rr]  (512B block per (t,g,cg,bg))
// ============================================================
#define P1_BM 128
#define P1_BK 32

__device__ __forceinline__ int p1swz(int r, int k) {
  return r * P1_BK + ((((k >> 3) ^ (r & 3)) << 3) | (k & 7));
}

__global__ __launch_bounds__(256, 2) void gru_xgemm(
    const float* __restrict__ inp, const float* __restrict__ Win,
    const float* __restrict__ bstk, h16* __restrict__ x) {
  __shared__ h16 sAh[2][P1_BM * P1_BK];
  __shared__ h16 sAl[2][P1_BM * P1_BK];
  __shared__ h16 sBh[2][P1_BM * P1_BK];
  __shared__ h16 sBl[2][P1_BM * P1_BK];

  const int tid = threadIdx.x;
  const int l = tid & 63;
  const int w = tid >> 6;
  const int wm = (w >> 1) * 64, wn = (w & 1) * 64;
  const int mi = blockIdx.x, ni = blockIdx.y;

  const int sr  = tid >> 1;
  const int skh = (tid & 1) * 16;

  const float* aSrcBase = inp + (size_t)(sr & 63) * (T_SEQ * NI)
                              + (size_t)(mi * 2 + (sr >> 6)) * NI + skh;
  const float* bSrcBase = Win + (size_t)skh * N3H + ni * 128 + sr;

  f32x4 acc[4][4] = {};
  float aReg[16];
  float bReg[16];

  auto stage_load = [&](int ks) {
    const float* ap = aSrcBase + ks * P1_BK;
    #pragma unroll
    for (int jg = 0; jg < 4; ++jg) {
      f32x4 v = *(const f32x4*)(ap + jg * 4);
      aReg[jg*4+0] = v[0]; aReg[jg*4+1] = v[1];
      aReg[jg*4+2] = v[2]; aReg[jg*4+3] = v[3];
    }
    const float* bp = bSrcBase + (size_t)ks * P1_BK * N3H;
    #pragma unroll
    for (int j = 0; j < 16; ++j) bReg[j] = bp[(size_t)j * N3H];
  };

  auto stage_write = [&](int buf) {
    #pragma unroll
    for (int jg = 0; jg < 4; ++jg) {
      int idx = p1swz(sr, skh + jg * 4);
      h16x4 hi, lo;
      #pragma unroll
      for (int j = 0; j < 4; ++j) {
        float v = aReg[jg*4+j];
        h16 h = (h16)v; hi[j] = h; lo[j] = (h16)(v - (float)h);
      }
      *(h16x4*)&sAh[buf][idx] = hi;
      *(h16x4*)&sAl[buf][idx] = lo;
      #pragma unroll
      for (int j = 0; j < 4; ++j) {
        float v = bReg[jg*4+j];
        h16 h = (h16)v; hi[j] = h; lo[j] = (h16)(v - (float)h);
      }
      *(h16x4*)&sBh[buf][idx] = hi;
      *(h16x4*)&sBl[buf][idx] = lo;
    }
  };

  auto compute = [&](int buf) {
    const int k0 = (l >> 4) * 8;
    h16x8 bh[4], bl[4];
    #pragma unroll
    for (int nt = 0; nt < 4; ++nt) {
      int idx = p1swz(wn + nt * 16 + (l & 15), k0);
      bh[nt] = *(const h16x8*)&sBh[buf][idx];
      bl[nt] = *(const h16x8*)&sBl[buf][idx];
    }
    #pragma unroll
    for (int mt = 0; mt < 4; ++mt) {
      int idx = p1swz(wm + mt * 16 + (l & 15), k0);
      h16x8 ah = *(const h16x8*)&sAh[buf][idx];
      h16x8 al = *(const h16x8*)&sAl[buf][idx];
      #pragma unroll
      for (int nt = 0; nt < 4; ++nt) {
        acc[mt][nt] = __builtin_amdgcn_mfma_f32_16x16x32_f16(ah, bh[nt], acc[mt][nt], 0, 0, 0);
        acc[mt][nt] = __builtin_amdgcn_mfma_f32_16x16x32_f16(ah, bl[nt], acc[mt][nt], 0, 0, 0);
        acc[mt][nt] = __builtin_amdgcn_mfma_f32_16x16x32_f16(al, bh[nt], acc[mt][nt], 0, 0, 0);
      }
    }
  };

  stage_load(0);
  stage_write(0);
  __syncthreads();
  for (int ks = 0; ks < 16; ++ks) {
    int buf = ks & 1;
    if (ks < 15) stage_load(ks + 1);
    compute(buf);
    if (ks < 15) stage_write(buf ^ 1);
    __syncthreads();
  }

  const int t = mi * 2 + (wm >> 6);
  const int rrb = (l >> 4) * 4;
  #pragma unroll
  for (int nt = 0; nt < 4; ++nt) {
    int colhi = ni * 8 + (wn >> 4) + nt;
    int gg  = colhi >> 6;
    int cgx = colhi & 63;
    float bias = bstk[(colhi << 4) + (l & 15)];
    #pragma unroll
    for (int mt = 0; mt < 4; ++mt) {
      h16x4 v;
      #pragma unroll
      for (int i = 0; i < 4; ++i) v[i] = (h16)(acc[mt][nt][i] + bias);
      size_t idx = ((((size_t)t * 3 + gg) * 64 + cgx) * 4 + mt) * 256
                 + (size_t)(l & 15) * 16 + rrb;
      *(h16x4*)&x[idx] = v;
    }
  }
}

// ============================================================
// Kernel 2: persistent GRU recurrence, self-validating h words,
// SENTINEL-then-BULK detect (r9): each thread polls ONE sentinel word
// per round (cg = tid&63, lane = wave id) — 60x less poll traffic than
// r7's poll-everything — then pulls the full plane once, with per-word
// tag retry as the correctness net.
// ============================================================
__global__ __launch_bounds__(192, 1) void gru_steps(
    const float* __restrict__ Whid,   // [1024][3072] f32
    const h16* __restrict__ x,        // transposed layout, f16
    u64* __restrict__ hfrag,          // [2 par][4 bg][4096] u64 packed
    const float* __restrict__ hid0,   // [1024]
    float* __restrict__ out) {        // [64][1024] f32
  __shared__ h16 U[3 * 32 * 64 * 8];  // 96 KiB fragment-ordered W_hid slice
  __shared__ h16 hstage[16384];       // 32 KiB unpacked h plane (frag order)
  __shared__ float rbuf[2][16 * 17];
  __shared__ float ubuf[2][16 * 17];
  __shared__ unsigned short tq[16 * 20];

  const int tid = threadIdx.x;
  const int l = tid & 63;
  const int g = tid >> 6;
  const int cg = blockIdx.x & 63;
  const int bg = blockIdx.x >> 6;

  // ---- one-time: W_hid slice -> fragment-ordered LDS ----
  {
    const float* base = Whid + (size_t)g * NH + (size_t)cg * 16 + (l & 15);
    for (int kt = 0; kt < 32; ++kt) {
      const float* src = base + (size_t)(kt * 32 + (l >> 4) * 8) * N3H;
      h16x8 v;
      #pragma unroll
      for (int j = 0; j < 8; ++j) v[j] = (h16)src[(size_t)j * N3H];
      *(h16x8*)&U[(size_t)((g * 32 + kt) * 64 + l) * 8] = v;
    }
  }

  const int rr0 = (l >> 4) * 4, cc = l & 15;

  // ---- wave2: persistent f32 h_prev registers (owner-only tile) ----
  float hq[4];
  if (g == 2) {
    float h0 = hid0[cg * 16 + cc];
    #pragma unroll
    for (int i = 0; i < 4; ++i) hq[i] = h0;
  }
  __syncthreads();

  // x pointer for this wave (one 8B load per step)
  const char* xb = (const char*)(x
      + ((((size_t)g * 64 + cg) * 4 + bg) * 256)
      + (size_t)cc * 16 + rr0);
  u64 xq = *(const u64*)xb;   // step-1 tile, prefetched

  const h16* Ug = &U[(size_t)g * 32 * 64 * 8];
  const float S = 1.0f / 8192.0f;
  const int sw = l * 64 + g;   // sentinel: cg = l (covers all 64), lane g

  for (int s = 1; s <= T_SEQ; ++s) {
    const u64* src = hfrag + ((size_t)((s - 1) & 1) * 4 + bg) * 4096;
    const unsigned expt = (((unsigned)(s - 1)) >> 1) & 15u;

    // prefetch next step's x tile (plain cached load, independent)
    u64 xq_next = xq;
    if (s < T_SEQ) xq_next = *(const u64*)(xb + (size_t)s * 393216);

    // ---- sentinel poll: 1 word/thread/round, all 64 cg covered/wave ----
    {
      int spincnt = 0;
      for (;;) {
        u64 sv = cload64(src + sw);
        if (__all((int)((((unsigned)(sv >> 28)) & 15u) == expt))) break;
        __builtin_amdgcn_s_sleep(1);
        if (++spincnt > 60000) break;   // hang-safety
      }
    }

    // ---- bulk pull of the plane (one round; per-word retry is rare) ----
    u64 w[22];
    #pragma unroll
    for (int k = 0; k < 22; ++k) {
      int wd = tid + 192 * k;
      w[k] = (wd < 4096) ? cload64(src + wd) : ((u64)expt << 28);
    }
    for (int tries = 0; tries < 10000; ++tries) {
      unsigned bad = 0;
      #pragma unroll
      for (int k = 0; k < 22; ++k)
        bad |= ((((unsigned)(w[k] >> 28)) & 15u) != expt) ? (1u << k) : 0u;
      if (bad == 0) break;
      #pragma unroll
      for (int k = 0; k < 22; ++k) {
        int wd = tid + 192 * k;
        if ((bad & (1u << k)) && wd < 4096) w[k] = cload64(src + wd);
      }
    }

    // ---- unpack q14 -> f16 frag into LDS ----
    #pragma unroll
    for (int k = 0; k < 22; ++k) {
      int wd = tid + 192 * k;
      if (wd < 4096) {
        unsigned lo = (unsigned)w[k], hi = (unsigned)(w[k] >> 32);
        h16x4 o;
        o[0] = (h16)((float)(((int)(lo << 18)) >> 18) * S);
        o[1] = (h16)((float)(((int)(lo << 4)) >> 18) * S);
        o[2] = (h16)((float)(((int)(hi << 18)) >> 18) * S);
        o[3] = (h16)((float)(((int)(hi << 4)) >> 18) * S);
        *(h16x4*)&hstage[wd * 4] = o;
      }
    }
    __syncthreads();   // b1: h staged

    // ---- hid = h_f16 @ U_gate : 32 MFMA, contiguous b128 reads ----
    f32x4 a0 = {}, a1 = {};
    #pragma unroll
    for (int kt = 0; kt < 32; ++kt) {
      h16x8 a = *(const h16x8*)&hstage[(kt * 64 + l) * 8];
      h16x8 b = *(const h16x8*)&Ug[(kt * 64 + l) * 8];
      if (kt & 1) a1 = __builtin_amdgcn_mfma_f32_16x16x32_f16(a, b, a1, 0, 0, 0);
      else        a0 = __builtin_amdgcn_mfma_f32_16x16x32_f16(a, b, a0, 0, 0, 0);
    }
    f32x4 hid;
    #pragma unroll
    for (int i = 0; i < 4; ++i) hid[i] = a0[i] + a1[i];

    H4 xc; xc.q = xq;
    const int p = s & 1;

    if (g == 0) {
      #pragma unroll
      for (int i = 0; i < 4; ++i) {
        float pr = (float)xc.v[i] + hid[i];
        rbuf[p][(rr0 + i) * 17 + cc] = 1.0f / (1.0f + __expf(-pr));
      }
    } else if (g == 1) {
      #pragma unroll
      for (int i = 0; i < 4; ++i) {
        float pu = (float)xc.v[i] + hid[i];
        ubuf[p][(rr0 + i) * 17 + cc] = 1.0f / (1.0f + __expf(-pu));
      }
    }
    __syncthreads();   // b2: r,u visible to wave 2

    if (g == 2) {
      const unsigned tag = (((unsigned)s) >> 1) & 15u;
      #pragma unroll
      for (int i = 0; i < 4; ++i) {
        int rr = rr0 + i;
        float r = rbuf[p][rr * 17 + cc];
        float u = ubuf[p][rr * 17 + cc];
        float z = (float)xc.v[i] + r * hid[i];
        float e = __expf(2.0f * z);
        float c = 1.0f - 2.0f / (e + 1.0f);      // tanh(z)
        float hn = (1.0f - u) * hq[i] + u * c;
        hq[i] = hn;
        int qv = (int)__builtin_rintf(fminf(hn * 8192.0f, 8191.0f));
        tq[rr * 20 + cc] = (unsigned short)(qv & 0x3FFF);
        if (s == T_SEQ) out[(size_t)(bg * 16 + rr) * NH + cg * 16 + cc] = hn;
      }
      u64 t = *(const u64*)&tq[((l >> 1) & 15) * 20 + (l >> 5) * 8 + (l & 1) * 4];
      unsigned lo = ((unsigned)t & 0x3FFFu)
                  | ((((unsigned)(t >> 16)) & 0x3FFFu) << 14) | (tag << 28);
      unsigned hi = (((unsigned)(t >> 32)) & 0x3FFFu)
                  | ((((unsigned)(t >> 48)) & 0x3FFFu) << 14);
      u64* dst = hfrag + (((size_t)(s & 1) * 4 + bg) * 4096) + cg * 64 + l;
      cstore64(dst, (u64)lo | ((u64)hi << 32));   // self-validating: no drain
    }
    xq = xq_next;
  }
}

// ============================================================
extern "C" void kernel_launch(void* const* d_in, const int* in_sizes, int n_in,
                              void* d_out, int out_size, void* d_ws, size_t ws_size,
                              hipStream_t stream) {
  const float* inp  = (const float*)d_in[0];
  const float* Win  = (const float*)d_in[1];
  const float* Whid = (const float*)d_in[2];
  const float* bstk = (const float*)d_in[3];
  const float* hid0 = (const float*)d_in[4];
  float* out = (float*)d_out;

  char* ws = (char*)d_ws;
  const size_t xBytes = (size_t)T_SEQ * NB * N3H * sizeof(h16);   // 201,326,592
  const size_t hBytes = (size_t)2 * 4 * 4096 * sizeof(u64);       //     262,144
  if (ws_size < xBytes + hBytes) return;

  h16* x = (h16*)ws;
  u64* hfrag = (u64*)(ws + xBytes);

  gru_init_h<<<dim3(16384 / 256), dim3(256), 0, stream>>>(hid0, hfrag);

  dim3 g1(32768 / P1_BM, N3H / 128);
  gru_xgemm<<<g1, dim3(256), 0, stream>>>(inp, Win, bstk, x);

  gru_steps<<<dim3(256), dim3(192), 0, stream>>>(Whid, x, hfrag, hid0, out);
}

// Round 10
// 2547.865 us; speedup vs baseline: 4.9373x; 1.1078x over previous
//
#include <hip/hip_runtime.h>
#include <hip/hip_fp16.h>
#include <math.h>

typedef _Float16 h16;
typedef __attribute__((ext_vector_type(4))) _Float16 h16x4;
typedef __attribute__((ext_vector_type(8))) _Float16 h16x8;
typedef __attribute__((ext_vector_type(4))) float f32x4;
typedef unsigned long long u64;

#define T_SEQ 512
#define NB    64
#define NI    512
#define NH    1024
#define N3H   3072

// Agent-scope (LLC-coherent) helpers. Relaxed per-access coherence only —
// no cache-wide fences (r2 lesson), no L2 relay (r8 lesson). Ordering is
// data stores -> vmcnt(0) drain -> tag store (r6-proven protocol).
__device__ __forceinline__ u64 cload64(const u64* p) {
  return __hip_atomic_load(p, __ATOMIC_RELAXED, __HIP_MEMORY_SCOPE_AGENT);
}
__device__ __forceinline__ void cstore64(u64* p, u64 v) {
  __hip_atomic_store(p, v, __ATOMIC_RELAXED, __HIP_MEMORY_SCOPE_AGENT);
}
__device__ __forceinline__ unsigned cload32(const unsigned* p) {
  return __hip_atomic_load(p, __ATOMIC_RELAXED, __HIP_MEMORY_SCOPE_AGENT);
}
__device__ __forceinline__ void cstore32(unsigned* p, unsigned v) {
  __hip_atomic_store(p, v, __ATOMIC_RELAXED, __HIP_MEMORY_SCOPE_AGENT);
}

union H4 { u64 q; h16x4 v; };
union F8 { u64 q[2]; h16x8 v; };

// h planes: [2 parity][4 bg][4096 u64] RAW f16 in MFMA-fragment order:
// 16B frag idx f = kt*64 + l  holds  h[row=l&15][k = kt*32 + (l>>4)*8 + 0..7].
// tags: [2 parity][4 bg][64 cg] u32 = producing step s (monotonic).

// ============================================================
// Kernel 0: init h^(0) parity-0 planes (raw f16 frag order).
// ============================================================
__global__ void gru_init_h(const float* __restrict__ hid0,
                           u64* __restrict__ hfrag) {
  int W = blockIdx.x * blockDim.x + threadIdx.x;   // 0..16383 (4 bg x 4096)
  if (W >= 16384) return;
  int bg = W >> 12;
  int w  = W & 4095;                 // u64 word within plane
  int kt = w >> 7;
  int lp = (w >> 1) & 63;
  int q  = w & 1;
  int cb = kt * 32 + ((lp >> 4) & 3) * 8 + q * 4;
  H4 o;
  #pragma unroll
  for (int j = 0; j < 4; ++j) o.v[j] = (h16)hid0[cb + j];  // row-independent
  hfrag[(size_t)bg * 4096 + w] = o.q;                      // parity-0 plane
}

// ============================================================
// Kernel 1: x = inp @ W_in + b  (f16 out, CONSUMER-TRANSPOSED layout)
// x layout: [t][gate][cg][bg][cc*16 + rr]  (512B block per (t,g,cg,bg))
// ============================================================
#define P1_BM 128
#define P1_BK 32

__device__ __forceinline__ int p1swz(int r, int k) {
  return r * P1_BK + ((((k >> 3) ^ (r & 3)) << 3) | (k & 7));
}

__global__ __launch_bounds__(256, 2) void gru_xgemm(
    const float* __restrict__ inp, const float* __restrict__ Win,
    const float* __restrict__ bstk, h16* __restrict__ x) {
  __shared__ h16 sAh[2][P1_BM * P1_BK];
  __shared__ h16 sAl[2][P1_BM * P1_BK];
  __shared__ h16 sBh[2][P1_BM * P1_BK];
  __shared__ h16 sBl[2][P1_BM * P1_BK];

  const int tid = threadIdx.x;
  const int l = tid & 63;
  const int w = tid >> 6;
  const int wm = (w >> 1) * 64, wn = (w & 1) * 64;
  const int mi = blockIdx.x, ni = blockIdx.y;

  const int sr  = tid >> 1;
  const int skh = (tid & 1) * 16;

  const float* aSrcBase = inp + (size_t)(sr & 63) * (T_SEQ * NI)
                              + (size_t)(mi * 2 + (sr >> 6)) * NI + skh;
  const float* bSrcBase = Win + (size_t)skh * N3H + ni * 128 + sr;

  f32x4 acc[4][4] = {};
  float aReg[16];
  float bReg[16];

  auto stage_load = [&](int ks) {
    const float* ap = aSrcBase + ks * P1_BK;
    #pragma unroll
    for (int jg = 0; jg < 4; ++jg) {
      f32x4 v = *(const f32x4*)(ap + jg * 4);
      aReg[jg*4+0] = v[0]; aReg[jg*4+1] = v[1];
      aReg[jg*4+2] = v[2]; aReg[jg*4+3] = v[3];
    }
    const float* bp = bSrcBase + (size_t)ks * P1_BK * N3H;
    #pragma unroll
    for (int j = 0; j < 16; ++j) bReg[j] = bp[(size_t)j * N3H];
  };

  auto stage_write = [&](int buf) {
    #pragma unroll
    for (int jg = 0; jg < 4; ++jg) {
      int idx = p1swz(sr, skh + jg * 4);
      h16x4 hi, lo;
      #pragma unroll
      for (int j = 0; j < 4; ++j) {
        float v = aReg[jg*4+j];
        h16 h = (h16)v; hi[j] = h; lo[j] = (h16)(v - (float)h);
      }
      *(h16x4*)&sAh[buf][idx] = hi;
      *(h16x4*)&sAl[buf][idx] = lo;
      #pragma unroll
      for (int j = 0; j < 4; ++j) {
        float v = bReg[jg*4+j];
        h16 h = (h16)v; hi[j] = h; lo[j] = (h16)(v - (float)h);
      }
      *(h16x4*)&sBh[buf][idx] = hi;
      *(h16x4*)&sBl[buf][idx] = lo;
    }
  };

  auto compute = [&](int buf) {
    const int k0 = (l >> 4) * 8;
    h16x8 bh[4], bl[4];
    #pragma unroll
    for (int nt = 0; nt < 4; ++nt) {
      int idx = p1swz(wn + nt * 16 + (l & 15), k0);
      bh[nt] = *(const h16x8*)&sBh[buf][idx];
      bl[nt] = *(const h16x8*)&sBl[buf][idx];
    }
    #pragma unroll
    for (int mt = 0; mt < 4; ++mt) {
      int idx = p1swz(wm + mt * 16 + (l & 15), k0);
      h16x8 ah = *(const h16x8*)&sAh[buf][idx];
      h16x8 al = *(const h16x8*)&sAl[buf][idx];
      #pragma unroll
      for (int nt = 0; nt < 4; ++nt) {
        acc[mt][nt] = __builtin_amdgcn_mfma_f32_16x16x32_f16(ah, bh[nt], acc[mt][nt], 0, 0, 0);
        acc[mt][nt] = __builtin_amdgcn_mfma_f32_16x16x32_f16(ah, bl[nt], acc[mt][nt], 0, 0, 0);
        acc[mt][nt] = __builtin_amdgcn_mfma_f32_16x16x32_f16(al, bh[nt], acc[mt][nt], 0, 0, 0);
      }
    }
  };

  stage_load(0);
  stage_write(0);
  __syncthreads();
  for (int ks = 0; ks < 16; ++ks) {
    int buf = ks & 1;
    if (ks < 15) stage_load(ks + 1);
    compute(buf);
    if (ks < 15) stage_write(buf ^ 1);
    __syncthreads();
  }

  const int t = mi * 2 + (wm >> 6);
  const int rrb = (l >> 4) * 4;
  #pragma unroll
  for (int nt = 0; nt < 4; ++nt) {
    int colhi = ni * 8 + (wn >> 4) + nt;
    int gg  = colhi >> 6;
    int cgx = colhi & 63;
    float bias = bstk[(colhi << 4) + (l & 15)];
    #pragma unroll
    for (int mt = 0; mt < 4; ++mt) {
      h16x4 v;
      #pragma unroll
      for (int i = 0; i < 4; ++i) v[i] = (h16)(acc[mt][nt][i] + bias);
      size_t idx = ((((size_t)t * 3 + gg) * 64 + cgx) * 4 + mt) * 256
                 + (size_t)(l & 15) * 16 + rrb;
      *(h16x4*)&x[idx] = v;
    }
  }
}

// ============================================================
// Kernel 2: persistent GRU recurrence — SINGLE-WAVE step loop.
// 256 WG = 64 cg x 4 bg. Prologue: 3 waves load U, then waves 1,2 exit.
// Per step (wave 0 only, no barriers): poll 64 tags (1 load/lane) ->
// pull 64 u64 = exactly this lane's 32 MFMA A-fragments (no LDS, no
// unpack) -> 96 MFMA (3 gates) -> gates in-register -> LDS transpose
// (lgkmcnt only) -> 1 cstore64/lane -> vmcnt(0) -> tag store.
// ============================================================
__global__ __launch_bounds__(192, 1) void gru_steps(
    const float* __restrict__ Whid,   // [1024][3072] f32
    const h16* __restrict__ x,        // transposed layout, f16
    u64* __restrict__ hfrag,          // [2 par][4 bg][4096] u64 raw-f16 frags
    unsigned* __restrict__ tags,      // [2 par][4 bg][64 cg]
    const float* __restrict__ hid0,   // [1024]
    float* __restrict__ out) {        // [64][1024] f32
  __shared__ h16 U[3 * 32 * 64 * 8];  // 96 KiB fragment-ordered W_hid slice
  __shared__ h16 tq[16 * 20];         // store-transpose staging

  const int tid = threadIdx.x;
  const int l = tid & 63;
  const int g = tid >> 6;
  const int cg = blockIdx.x & 63;
  const int bg = blockIdx.x >> 6;

  // ---- one-time: W_hid slice -> fragment-ordered LDS (3 waves) ----
  {
    const float* base = Whid + (size_t)g * NH + (size_t)cg * 16 + (l & 15);
    for (int kt = 0; kt < 32; ++kt) {
      const float* src = base + (size_t)(kt * 32 + (l >> 4) * 8) * N3H;
      h16x8 v;
      #pragma unroll
      for (int j = 0; j < 8; ++j) v[j] = (h16)src[(size_t)j * N3H];
      *(h16x8*)&U[(size_t)((g * 32 + kt) * 64 + l) * 8] = v;
    }
  }
  __syncthreads();
  if (g != 0) return;    // steps run on wave 0 only (no more barriers)

  const int rr0 = (l >> 4) * 4, cc = l & 15;

  // persistent f32 h_prev (this WG's 16x16 tile lives only here)
  float hq[4];
  {
    float h0 = hid0[cg * 16 + cc];
    #pragma unroll
    for (int i = 0; i < 4; ++i) hq[i] = h0;
  }

  // x pointers: one 8B load per gate per step
  const char* xb0 = (const char*)(x + ((((size_t)0 * 64 + cg) * 4 + bg) * 256)
                                    + (size_t)cc * 16 + rr0);
  const char* xb1 = xb0 + 64 * 4 * 256 * 2;       // gate stride in bytes
  const char* xb2 = xb1 + 64 * 4 * 256 * 2;
  u64 xq0 = *(const u64*)xb0, xq1 = *(const u64*)xb1, xq2 = *(const u64*)xb2;

  // store-side destination word index (derived in journal; bijective):
  const int dstw = cg * 64 + ((l >> 4) >> 1) * 32 + (l & 15) * 2 + ((l >> 4) & 1);

  for (int s = 1; s <= T_SEQ; ++s) {
    const int par = (s - 1) & 1;
    const u64* plane = hfrag + ((size_t)par * 4 + bg) * 4096;
    const unsigned* tgin = tags + (par * 4 + bg) * 64;

    // ---- poll: 64 tags, 1 load/lane/round ----
    {
      const unsigned need = (unsigned)(s - 1);
      int spincnt = 0;
      for (;;) {
        unsigned tv = cload32(tgin + l);
        if (__all((int)(tv >= need))) break;
        __builtin_amdgcn_s_sleep(1);
        if (++spincnt > 200000) break;   // hang-safety
      }
    }
    __builtin_amdgcn_sched_barrier(0);

    // ---- prefetch next step's x tiles (plain cached loads) ----
    u64 xn0 = xq0, xn1 = xq1, xn2 = xq2;
    if (s < T_SEQ) {
      xn0 = *(const u64*)(xb0 + (size_t)s * 393216);
      xn1 = *(const u64*)(xb1 + (size_t)s * 393216);
      xn2 = *(const u64*)(xb2 + (size_t)s * 393216);
    }

    // ---- pull this lane's 32 A-fragments (64 coherent u64 loads) ----
    u64 A[64];
    #pragma unroll
    for (int kt = 0; kt < 32; ++kt) {
      A[2 * kt]     = cload64(plane + ((size_t)kt * 64 + l) * 2);
      A[2 * kt + 1] = cload64(plane + ((size_t)kt * 64 + l) * 2 + 1);
    }

    // ---- 96 MFMA: 3 independent gate chains, A reused 3x ----
    f32x4 ac0 = {}, ac1 = {}, ac2 = {};
    #pragma unroll
    for (int kt = 0; kt < 32; ++kt) {
      F8 f; f.q[0] = A[2 * kt]; f.q[1] = A[2 * kt + 1];
      h16x8 b0 = *(const h16x8*)&U[(size_t)((0 * 32 + kt) * 64 + l) * 8];
      h16x8 b1 = *(const h16x8*)&U[(size_t)((1 * 32 + kt) * 64 + l) * 8];
      h16x8 b2 = *(const h16x8*)&U[(size_t)((2 * 32 + kt) * 64 + l) * 8];
      ac0 = __builtin_amdgcn_mfma_f32_16x16x32_f16(f.v, b0, ac0, 0, 0, 0);
      ac1 = __builtin_amdgcn_mfma_f32_16x16x32_f16(f.v, b1, ac1, 0, 0, 0);
      ac2 = __builtin_amdgcn_mfma_f32_16x16x32_f16(f.v, b2, ac2, 0, 0, 0);
    }

    // ---- gates fully in-register ----
    H4 xr; xr.q = xq0;
    H4 xu; xu.q = xq1;
    H4 xc; xc.q = xq2;
    #pragma unroll
    for (int i = 0; i < 4; ++i) {
      float r = 1.0f / (1.0f + __expf(-((float)xr.v[i] + ac0[i])));
      float u = 1.0f / (1.0f + __expf(-((float)xu.v[i] + ac1[i])));
      float z = (float)xc.v[i] + r * ac2[i];
      float e = __expf(2.0f * z);
      float c = 1.0f - 2.0f / (e + 1.0f);      // tanh(z)
      float hn = (1.0f - u) * hq[i] + u * c;
      hq[i] = hn;
      tq[(rr0 + i) * 20 + cc] = (h16)hn;
      if (s == T_SEQ) out[(size_t)(bg * 16 + rr0 + i) * NH + cg * 16 + cc] = hn;
    }

    // ---- wave-local transpose -> one coalesced 8B store + tag ----
    H4 pv; pv.v = *(const h16x4*)&tq[(l & 15) * 20 + (l >> 4) * 4];
    u64* outp = hfrag + ((size_t)(s & 1) * 4 + bg) * 4096;
    cstore64(outp + dstw, pv.q);
    asm volatile("s_waitcnt vmcnt(0)" ::: "memory");   // data at LLC first
    __builtin_amdgcn_sched_barrier(0);
    if (l == 0)
      cstore32(tags + ((s & 1) * 4 + bg) * 64 + cg, (unsigned)s);

    xq0 = xn0; xq1 = xn1; xq2 = xn2;
  }
}

// ============================================================
extern "C" void kernel_launch(void* const* d_in, const int* in_sizes, int n_in,
                              void* d_out, int out_size, void* d_ws, size_t ws_size,
                              hipStream_t stream) {
  const float* inp  = (const float*)d_in[0];
  const float* Win  = (const float*)d_in[1];
  const float* Whid = (const float*)d_in[2];
  const float* bstk = (const float*)d_in[3];
  const float* hid0 = (const float*)d_in[4];
  float* out = (float*)d_out;

  char* ws = (char*)d_ws;
  const size_t xBytes = (size_t)T_SEQ * NB * N3H * sizeof(h16);   // 201,326,592
  const size_t hBytes = (size_t)2 * 4 * 4096 * sizeof(u64);       //     262,144
  const size_t tBytes = 2 * 4 * 64 * sizeof(unsigned);            //       2,048
  if (ws_size < xBytes + hBytes + tBytes) return;

  h16* x = (h16*)ws;
  u64* hfrag = (u64*)(ws + xBytes);
  unsigned* tags = (unsigned*)(ws + xBytes + hBytes);

  hipMemsetAsync(tags, 0, tBytes, stream);   // parity-0 ready (tag 0), parity-1 gated

  gru_init_h<<<dim3(16384 / 256), dim3(256), 0, stream>>>(hid0, hfrag);

  dim3 g1(32768 / P1_BM, N3H / 128);
  gru_xgemm<<<g1, dim3(256), 0, stream>>>(inp, Win, bstk, x);

  gru_steps<<<dim3(256), dim3(192), 0, stream>>>(Whid, x, hfrag, tags, hid0, out);
}